// Round 5
// baseline (101596.014 us; speedup 1.0000x reference)
//
#include <hip/hip_runtime.h>

// NeuralCDEDecoder: B=512, T=257, IN=32, H=128, BN=256, OUT=64, K_SUB=4.
// R10: 8-way h-split x 2 batch-sets per block. 256 blocks = 32 pairs x 8
// h-octants (1 block/CU). Each block runs TWO groups of 8 batch rows
// (gA=pair*2, gB=pair*2+1) phase-staggered inside each RK4 stage:
//   A.compute+pubA | postA+pollB | recvB | B.compute+pubB | postB+pollA | recvA
// so each flag poll targets flags posted ~one set-compute (~3us) earlier ->
// the cross-XCD exchange RTT (the R6/R9 bottleneck, ~3-4us/stage exposed)
// is hidden behind compute. Flag protocol = proven R6 primitives, two
// monotone posts per stage (2*stg, 2*stg+1), waits use >=.
// Per-set L3 is halved (1 h per wave); W3 per oct = 256KB, 16/32 ntiles
// cached in LDS (128KB) -> stream 128KB + W1/W2 192KB per stage per CU.
// Biases live in registers (LDS freed for 2nd bufZ/dxs). Decoder shifted
// to stage-top (reads z(t[ti]) -> output ti-1) + epilogue for output 255.
// fp32 state, hi/lo bf16 activations (bitwise-identical math per row).

using short8   = __attribute__((ext_vector_type(8))) short;
using float4v  = __attribute__((ext_vector_type(4))) float;

__device__ unsigned short g_w1p[32768];
__device__ unsigned short g_w2p[65536];
__device__ unsigned short g_w3p[1048576];
__device__ unsigned short g_mwp[8192];
__device__ unsigned short g_swp[8192];

__device__ int   g_flag[256];               // monotone: 2*stg after pubA, 2*stg+1 after pubB
__device__ float g_zx[2 * 64 * 8 * 128];    // [parity][group][oct][8rows*16dims]

__global__ void reset_flags(){
  if (threadIdx.x < 256) g_flag[threadIdx.x] = -1;
}

__device__ __forceinline__ unsigned short* pack_dst(int which){
  switch (which){
    case 0:  return g_w1p;
    case 1:  return g_w2p;
    case 2:  return g_w3p;
    case 3:  return g_mwp;
    default: return g_swp;
  }
}

__device__ __forceinline__ float bf2f(unsigned short h){
  union { unsigned int u; float f; } v; v.u = ((unsigned int)h) << 16; return v.f;
}
__device__ __forceinline__ unsigned short f2bf(float f){
  union { float f; unsigned int u; } v; v.f = f;
  unsigned int u = v.u;
  return (unsigned short)((u + 0x7FFFu + ((u >> 16) & 1u)) >> 16);  // RNE
}
template<bool BF16> __device__ __forceinline__ float loadf(const void* p, long i){
  if constexpr (BF16) return bf2f(((const unsigned short*)p)[i]);
  else                return ((const float*)p)[i];
}
// t[0]=0.0 always; bytes 2..3 are high half of f32 t[0] (=0) or bf16 t[1] (!=0).
__device__ __forceinline__ bool input_is_bf16(const void* t){
  return ((const unsigned short*)t)[1] != 0;
}
__device__ __forceinline__ float tanh_f(float x){
  float e = __builtin_amdgcn_exp2f(x * 2.88539008177793f);          // e^{2x}
  return 1.f - 2.f * __builtin_amdgcn_rcpf(e + 1.f);
}
__device__ __forceinline__ float softplus_f(float x){
  if (x > 20.f) return x;
  float e = __builtin_amdgcn_exp2f(x * 1.44269504088896f);
  return __builtin_amdgcn_logf(1.f + e) * 0.693147180559945f;       // log2->ln
}
// Sum across each 16-lane row; full sum lands in lane 15 of the row (VALU DPP).
__device__ __forceinline__ float row_sum16(float v){
  int x;
  x = __builtin_amdgcn_update_dpp(0, __float_as_int(v), 0x118, 0xF, 0xF, true); // row_shr:8
  v += __int_as_float(x);
  x = __builtin_amdgcn_update_dpp(0, __float_as_int(v), 0x114, 0xF, 0xF, true); // row_shr:4
  v += __int_as_float(x);
  x = __builtin_amdgcn_update_dpp(0, __float_as_int(v), 0x112, 0xF, 0xF, true); // row_shr:2
  v += __int_as_float(x);
  x = __builtin_amdgcn_update_dpp(0, __float_as_int(v), 0x111, 0xF, 0xF, true); // row_shr:1
  v += __int_as_float(x);
  return v;
}

// Pack row-major [K,N] weight into fragment order:
// tile (nt,kt) -> 512 bf16 at ((nt*KT+kt)<<9); elem (lane,j) = W[kt*32+(lane>>4)*8+j][nt*16+(lane&15)]
template<bool BF16>
__global__ __launch_bounds__(256)
void pack_weight(const void* __restrict__ src, int which,
                 int K, int N, const void* __restrict__ tchk){
  if (input_is_bf16(tchk) != BF16) return;
  unsigned short* dst = pack_dst(which);
  const int KT = K >> 5;
  const long total = (long)(N >> 4) * KT * 512;
  for (long e = (long)blockIdx.x * blockDim.x + threadIdx.x; e < total;
       e += (long)gridDim.x * blockDim.x){
    int  r    = (int)(e & 511);
    long tile = e >> 9;
    int  kt   = (int)(tile % KT);
    int  nt   = (int)(tile / KT);
    int  ln   = r >> 3, j = r & 7;
    int  k    = (kt << 5) + ((ln >> 4) << 3) + j;
    int  n    = (nt << 4) + (ln & 15);
    long si   = (long)k * N + n;
    dst[e] = BF16 ? ((const unsigned short*)src)[si] : f2bf(((const float*)src)[si]);
  }
}

#define STRZ 136   // z buffer row stride (bf16), 16 rows = hi/lo x 8 batch rows
#define STRH 264   // h buffer row stride (bf16), 16 rows = hi/lo x 8
#define STRVW 20   // vf row stride (fp32), 8 rows x 16 own h
#define STRD 33    // dxdt row stride (fp32), 8 rows

template<bool BF16>
__global__ __launch_bounds__(1024, 4)
void cde_main(const void* __restrict__ tin,  const void* __restrict__ z0in,
              const void* __restrict__ Xin,
              const void* __restrict__ b1in, const void* __restrict__ b2in,
              const void* __restrict__ b3in, const void* __restrict__ mbin,
              const void* __restrict__ sbin,
              void* __restrict__ outv)
{
  if (input_is_bf16(tin) != BF16) return;

  const unsigned short* __restrict__ w1p = g_w1p;
  const unsigned short* __restrict__ w2p = g_w2p;
  const unsigned short* __restrict__ w3p = g_w3p;
  const unsigned short* __restrict__ mwp = g_mwp;
  const unsigned short* __restrict__ swp = g_swp;

  __shared__ __align__(16) unsigned short bufZA[16 * STRZ];
  __shared__ __align__(16) unsigned short bufZB[16 * STRZ];
  __shared__ __align__(16) unsigned short bufH1[16 * STRH];
  __shared__ __align__(16) unsigned short bufH2[16 * STRH];
  __shared__ __align__(16) float          vfs  [ 8 * STRVW];
  __shared__ __align__(16) float          dxsA [ 8 * STRD];
  __shared__ __align__(16) float          dxsB [ 8 * STRD];
  __shared__ __align__(16) unsigned short w3c  [16 * 8 * 512];   // 128KB, oct ntiles 0..15

  const int tid  = threadIdx.x;
  const int lane = tid & 63;
  const int wv   = tid >> 6;          // wave 0..15
  const int c16  = lane & 15;
  const int quad = lane >> 4;
  const int ho   = blockIdx.x & 7;    // h-octant: h in [ho*16, ho*16+16)
  const int pair = blockIdx.x >> 3;   // 0..31
  const int gA   = pair * 2;          // group of set A
  const int gB   = pair * 2 + 1;      // group of set B
  const int m0A  = gA * 8;
  const int m0B  = gB * 8;

  // biases -> registers (no LDS)
  const float b1v  = loadf<BF16>(b1in, wv * 16 + c16);
  const float b2v  = loadf<BF16>(b2in, wv * 16 + c16);
  const float b3v0 = loadf<BF16>(b3in, ho * 512 + (wv * 2    ) * 16 + c16);
  const float b3v1 = loadf<BF16>(b3in, ho * 512 + (wv * 2 + 1) * 16 + c16);
  const float mbv  = loadf<BF16>(mbin, (wv & 3) * 16 + c16);
  const float sbv  = loadf<BF16>(sbin, (wv & 3) * 16 + c16);

  // W3 LDS cache: local ntiles [0,16) = global ntiles ho*32 .. +15
  {
    const unsigned short* src = w3p + ((long)(ho * 256) << 9);
    for (int e = tid * 8; e < 16 * 8 * 512; e += 1024 * 8)
      *(short8*)&w3c[e] = *(const short8*)&src[e];
  }

  // W1/W2 fragments (wave wv owns ntile wv of each layer; compiler may remat)
  short8 w1f[4], w2f[8];
  {
    const unsigned short* p1 = w1p + ((long)(wv * 4) << 9) + lane * 8;
    #pragma unroll
    for (int kt = 0; kt < 4; ++kt) w1f[kt] = *(const short8*)(p1 + (kt << 9));
    const unsigned short* p2 = w2p + ((long)(wv * 8) << 9) + lane * 8;
    #pragma unroll
    for (int kt = 0; kt < 8; ++kt) w2f[kt] = *(const short8*)(p2 + (kt << 9));
  }

  // per-thread z state: thread owns dim zd of sub-row zm, for BOTH sets.
  const int  zm   = tid >> 7;         // 0..7
  const int  zd   = tid & 127;        // 0..127
  const int  q    = zd >> 4;          // octant of this dim
  const bool own  = (q == ho);
  const int  xidx = zm * 16 + (zd & 15);
  float zA = loadf<BF16>(z0in, (long)(m0A + zm) * 128 + zd);
  float zB = loadf<BF16>(z0in, (long)(m0B + zm) * 128 + zd);
  float zaccA = 0.f, zaccB = 0.f;
  {
    unsigned short h;
    h = f2bf(zA);
    bufZA[(2 * zm) * STRZ + zd] = h;  bufZA[(2 * zm + 1) * STRZ + zd] = f2bf(zA - bf2f(h));
    h = f2bf(zB);
    bufZB[(2 * zm) * STRZ + zd] = h;  bufZB[(2 * zm + 1) * STRZ + zd] = f2bf(zB - bf2f(h));
  }
  __syncthreads();                                   // init (w3c, bufZ) ready

#define LAYER1(ZBUF) do{                                                        \
    short8 a_[4];                                                               \
    _Pragma("unroll") for (int kt = 0; kt < 4; ++kt)                            \
      a_[kt] = *(const short8*)&ZBUF[c16 * STRZ + kt * 32 + quad * 8];          \
    float4v acc_ = {0.f,0.f,0.f,0.f};                                           \
    _Pragma("unroll") for (int kt = 0; kt < 4; ++kt)                            \
      acc_ = __builtin_amdgcn_mfma_f32_16x16x32_bf16(a_[kt], w1f[kt], acc_, 0,0,0); \
    _Pragma("unroll") for (int s = 0; s < 2; ++s){                              \
      float v_ = acc_[2*s] + acc_[2*s+1] + b1v;                                 \
      v_ = v_ > 0.f ? v_ : 0.f;                                                 \
      unsigned short h_ = f2bf(v_);                                             \
      const int row_ = quad * 4 + 2 * s;                                        \
      bufH1[ row_      * STRH + wv * 16 + c16] = h_;                            \
      bufH1[(row_ + 1) * STRH + wv * 16 + c16] = f2bf(v_ - bf2f(h_));           \
    }                                                                           \
  }while(0)

#define LAYER2() do{                                                            \
    short8 a_[8];                                                               \
    _Pragma("unroll") for (int kt = 0; kt < 8; ++kt)                            \
      a_[kt] = *(const short8*)&bufH1[c16 * STRH + kt * 32 + quad * 8];         \
    float4v acc_ = {0.f,0.f,0.f,0.f};                                           \
    _Pragma("unroll") for (int kt = 0; kt < 8; ++kt)                            \
      acc_ = __builtin_amdgcn_mfma_f32_16x16x32_bf16(a_[kt], w2f[kt], acc_, 0,0,0); \
    _Pragma("unroll") for (int s = 0; s < 2; ++s){                              \
      float v_ = acc_[2*s] + acc_[2*s+1] + b2v;                                 \
      v_ = v_ > 0.f ? v_ : 0.f;                                                 \
      unsigned short h_ = f2bf(v_);                                             \
      const int row_ = quad * 4 + 2 * s;                                        \
      bufH2[ row_      * STRH + wv * 16 + c16] = h_;                            \
      bufH2[(row_ + 1) * STRH + wv * 16 + c16] = f2bf(v_ - bf2f(h_));           \
    }                                                                           \
  }while(0)

#define L3TILE(NTL, BV, ACC) do{                                                \
    if (wv < 8){                                                                \
      const unsigned short* cp_ = w3c + (((NTL) * 8) << 9) + lane * 8;          \
      _Pragma("unroll") for (int kh = 0; kh < 2; ++kh){                         \
        short8 b_[4];                                                           \
        _Pragma("unroll") for (int kt = 0; kt < 4; ++kt)                        \
          b_[kt] = *(const short8*)(cp_ + ((kh * 4 + kt) << 9));                \
        _Pragma("unroll") for (int kt = 0; kt < 4; ++kt)                        \
          ACC = __builtin_amdgcn_mfma_f32_16x16x32_bf16(a_[kh*4+kt], b_[kt], ACC, 0,0,0); \
      }                                                                         \
    } else {                                                                    \
      const unsigned short* wp_ = w3p + (((long)((ho * 32 + (NTL)) * 8)) << 9) + lane * 8; \
      _Pragma("unroll") for (int kh = 0; kh < 2; ++kh){                         \
        short8 b_[4];                                                           \
        _Pragma("unroll") for (int kt = 0; kt < 4; ++kt)                        \
          b_[kt] = *(const short8*)(wp_ + ((kh * 4 + kt) << 9));                \
        _Pragma("unroll") for (int kt = 0; kt < 4; ++kt)                        \
          ACC = __builtin_amdgcn_mfma_f32_16x16x32_bf16(a_[kh*4+kt], b_[kt], ACC, 0,0,0); \
      }                                                                         \
    }                                                                           \
  }while(0)

#define LAYER3(DXS) do{                                                         \
    short8 a_[8];                                                               \
    _Pragma("unroll") for (int kt = 0; kt < 8; ++kt)                            \
      a_[kt] = *(const short8*)&bufH2[c16 * STRH + kt * 32 + quad * 8];         \
    float dd0_[2], dd1_[2];                                                     \
    _Pragma("unroll") for (int s = 0; s < 2; ++s){                              \
      dd0_[s] = DXS[(quad * 2 + s) * STRD + c16];                               \
      dd1_[s] = DXS[(quad * 2 + s) * STRD + 16 + c16];                          \
    }                                                                           \
    const int lnt_ = wv * 2;                                                    \
    float t0_[2], t1_[2];                                                       \
    {                                                                           \
      float4v acc_ = {0.f,0.f,0.f,0.f};                                         \
      L3TILE(lnt_, b3v0, acc_);                                                 \
      _Pragma("unroll") for (int s = 0; s < 2; ++s)                             \
        t0_[s] = tanh_f(acc_[2*s] + acc_[2*s+1] + b3v0) * dd0_[s];              \
    }                                                                           \
    {                                                                           \
      float4v acc_ = {0.f,0.f,0.f,0.f};                                         \
      L3TILE(lnt_ + 1, b3v1, acc_);                                             \
      _Pragma("unroll") for (int s = 0; s < 2; ++s)                             \
        t1_[s] = tanh_f(acc_[2*s] + acc_[2*s+1] + b3v1) * dd1_[s];              \
    }                                                                           \
    _Pragma("unroll") for (int s = 0; s < 2; ++s){                              \
      float r_ = row_sum16(t0_[s] + t1_[s]);                                    \
      if (c16 == 15) vfs[(quad * 2 + s) * STRVW + wv] = r_;                     \
    }                                                                           \
  }while(0)

#define RK4PUB(ZV, ZACC, ZBUF, GSLOT) do{                                       \
    if (own){                                                                   \
      const float k_ = vfs[zm * STRVW + (zd & 15)];                             \
      float nin_;                                                               \
      if (st == 0){ ZACC = ZV + (hs * (1.f/6.f)) * k_; nin_ = ZV + 0.5f*hs*k_; }\
      else if (st == 1){ ZACC += (hs * (1.f/3.f)) * k_; nin_ = ZV + 0.5f*hs*k_; }\
      else if (st == 2){ ZACC += (hs * (1.f/3.f)) * k_; nin_ = ZV + hs*k_; }    \
      else { ZV = ZACC + (hs * (1.f/6.f)) * k_; nin_ = ZV; }                    \
      __hip_atomic_store((int*)&g_zx[((par * 64 + (GSLOT)) * 8 + ho) * 128 + xidx], \
                         __float_as_int(nin_),                                  \
                         __ATOMIC_RELAXED, __HIP_MEMORY_SCOPE_AGENT);           \
      unsigned short h_ = f2bf(nin_);                                           \
      ZBUF[(2 * zm    ) * STRZ + zd] = h_;                                      \
      ZBUF[(2 * zm + 1) * STRZ + zd] = f2bf(nin_ - bf2f(h_));                   \
    }                                                                           \
  }while(0)

#define POST(V) do{                                                             \
    if (tid == 0)                                                               \
      __hip_atomic_store(&g_flag[blockIdx.x], (V),                              \
                         __ATOMIC_RELEASE, __HIP_MEMORY_SCOPE_AGENT);           \
  }while(0)

#define POLL(TGT) do{                                                           \
    if (tid >= 1 && tid < 8){                                                   \
      const int p_ = (pair << 3) | ((ho + tid) & 7);                            \
      while (__hip_atomic_load(&g_flag[p_],                                     \
                               __ATOMIC_ACQUIRE, __HIP_MEMORY_SCOPE_AGENT) < (TGT)) \
        __builtin_amdgcn_s_sleep(2);                                            \
    }                                                                           \
  }while(0)

#define RECV(ZBUF, GSLOT, PARR) do{                                             \
    if (!own){                                                                  \
      int u_ = __hip_atomic_load(                                               \
                 (const int*)&g_zx[(((PARR) * 64 + (GSLOT)) * 8 + q) * 128 + xidx], \
                 __ATOMIC_RELAXED, __HIP_MEMORY_SCOPE_AGENT);                   \
      float v_ = __int_as_float(u_);                                            \
      unsigned short h_ = f2bf(v_);                                             \
      ZBUF[(2 * zm    ) * STRZ + zd] = h_;                                      \
      ZBUF[(2 * zm + 1) * STRZ + zd] = f2bf(v_ - bf2f(h_));                     \
    }                                                                           \
  }while(0)

#define DECODE(ZBUF, M0S, ISSTD, OTI) do{                                       \
    short8 a_[4];                                                               \
    _Pragma("unroll") for (int kt = 0; kt < 4; ++kt)                            \
      a_[kt] = *(const short8*)&ZBUF[c16 * STRZ + kt * 32 + quad * 8];          \
    const unsigned short* wp_ = ((ISSTD) ? swp : mwp)                           \
                                + ((long)((wv & 3) * 4) << 9) + lane * 8;       \
    short8 b_[4];                                                               \
    _Pragma("unroll") for (int kt = 0; kt < 4; ++kt)                            \
      b_[kt] = *(const short8*)(wp_ + (kt << 9));                               \
    float4v acc_ = {0.f,0.f,0.f,0.f};                                           \
    _Pragma("unroll") for (int kt = 0; kt < 4; ++kt)                            \
      acc_ = __builtin_amdgcn_mfma_f32_16x16x32_bf16(a_[kt], b_[kt], acc_, 0,0,0); \
    const float bv_ = (ISSTD) ? sbv : mbv;                                      \
    const long  ob_ = (ISSTD) ? 8388608L : 0L;                                  \
    _Pragma("unroll") for (int s = 0; s < 2; ++s){                              \
      float v_ = acc_[2*s] + acc_[2*s+1] + bv_;                                 \
      if (ISSTD) v_ = softplus_f(v_);                                           \
      long oi_ = ob_ + ((long)((M0S) + quad * 2 + s) * 256 + (OTI)) * 64        \
                     + (wv & 3) * 16 + c16;                                     \
      if constexpr (BF16) ((unsigned short*)outv)[oi_] = f2bf(v_);              \
      else                ((float*)outv)[oi_] = v_;                             \
    }                                                                           \
  }while(0)

  for (int ti = 0; ti < 256; ++ti){
    const float dt = loadf<BF16>(tin, ti + 1) - loadf<BF16>(tin, ti);
    const float hs = dt * 0.25f;                       // RK4 substep h

    for (int sub = 0; sub < 4; ++sub){
      for (int st = 0; st < 4; ++st){
        const int  stg     = (ti << 4) + (sub << 2) + st;   // 0..4095
        const int  par     = stg & 1;
        const bool tistart = (sub == 0 && st == 0);

        // ---- P1: (dxs @ ti start) + (decoder A, output ti-1) + A.L1
        if (tistart && tid < 512){
          const int setb = tid >> 8, m = (tid >> 5) & 7, i = tid & 31;
          const int m0s  = setb ? m0B : m0A;
          float xc = loadf<BF16>(Xin, ((long)(m0s + m) * 257 + ti    ) * 32 + i);
          float xn = loadf<BF16>(Xin, ((long)(m0s + m) * 257 + ti + 1) * 32 + i);
          float* dx = setb ? dxsB : dxsA;
          dx[m * STRD + i] = (xn - xc) / dt;
        }
        if (tistart && ti > 0 && ho < 2 && wv < 4)
          DECODE(bufZA, m0A, ho == 1, ti - 1);
        LAYER1(bufZA);
        __syncthreads();                               // [B-a]
        LAYER2();
        __syncthreads();                               // [C-a]
        LAYER3(dxsA);
        __syncthreads();                               // [D-a]
        RK4PUB(zA, zaccA, bufZA, gA);
        __syncthreads();                               // [E-a] drains pubA stores
        POST(2 * stg);                                 // flagA(stg)
        if (stg > 0) POLL(2 * stg - 1);                // partners' flagB(stg-1), ~3us stale
        __syncthreads();                               // [W-b]
        if (stg > 0) RECV(bufZB, gB, par ^ 1);         // B input published at stg-1
        __syncthreads();                               // [F-b]

        // ---- P7: (decoder B, output ti-1) + B.L1
        if (tistart && ti > 0 && (ho == 2 || ho == 3) && wv < 4)
          DECODE(bufZB, m0B, ho == 3, ti - 1);
        LAYER1(bufZB);
        __syncthreads();                               // [B-b]
        LAYER2();
        __syncthreads();                               // [C-b]
        LAYER3(dxsB);
        __syncthreads();                               // [D-b]
        RK4PUB(zB, zaccB, bufZB, gB);
        __syncthreads();                               // [E-b] drains pubB stores
        POST(2 * stg + 1);                             // flagB(stg)
        POLL(2 * stg);                                 // partners' flagA(stg), ~3us stale
        __syncthreads();                               // [W-a]
        RECV(bufZA, gA, par);                          // A input published at stg
        __syncthreads();                               // [F-a]
      } // st
    } // sub
  } // ti

  // ---- epilogue: output index 255 = z(t[256]).
  // bufZA complete (last RECV). bufZB remote parts of stage-4095 pub not yet
  // received by ho 2/3 decoders -> final poll+recv for those blocks.
  if (ho == 2 || ho == 3){
    POLL(2 * 4095 + 1);
    __syncthreads();
    RECV(bufZB, gB, 1);                                // 4095 & 1 == 1
    __syncthreads();
  }
  if (ho < 2 && wv < 4)             DECODE(bufZA, m0A, ho == 1, 255);
  if ((ho == 2 || ho == 3) && wv < 4) DECODE(bufZB, m0B, ho == 3, 255);

#undef LAYER1
#undef LAYER2
#undef L3TILE
#undef LAYER3
#undef RK4PUB
#undef POST
#undef POLL
#undef RECV
#undef DECODE
}

extern "C" void kernel_launch(void* const* d_in, const int* in_sizes, int n_in,
                              void* d_out, int out_size, void* d_ws, size_t ws_size,
                              hipStream_t stream)
{
  const void* t  = d_in[0];
  const void* z0 = d_in[1];
  const void* X  = d_in[2];
  const void* W1 = d_in[3];
  const void* b1 = d_in[4];
  const void* W2 = d_in[5];
  const void* b2 = d_in[6];
  const void* W3 = d_in[7];
  const void* b3 = d_in[8];
  const void* mW = d_in[9];
  const void* mb = d_in[10];
  const void* sW = d_in[11];
  const void* sb = d_in[12];

  // Both dtype variants launched; each checks input dtype and the
  // non-matching one returns immediately (t[0]==0.0 discriminator).
  pack_weight<true ><<<256, 256, 0, stream>>>(W1, 0, 128,  256, t);
  pack_weight<true ><<<256, 256, 0, stream>>>(W2, 1, 256,  256, t);
  pack_weight<true ><<<512, 256, 0, stream>>>(W3, 2, 256, 4096, t);
  pack_weight<true ><<< 64, 256, 0, stream>>>(mW, 3, 128,   64, t);
  pack_weight<true ><<< 64, 256, 0, stream>>>(sW, 4, 128,   64, t);
  pack_weight<false><<<256, 256, 0, stream>>>(W1, 0, 128,  256, t);
  pack_weight<false><<<256, 256, 0, stream>>>(W2, 1, 256,  256, t);
  pack_weight<false><<<512, 256, 0, stream>>>(W3, 2, 256, 4096, t);
  pack_weight<false><<< 64, 256, 0, stream>>>(mW, 3, 128,   64, t);
  pack_weight<false><<< 64, 256, 0, stream>>>(sW, 4, 128,   64, t);

  reset_flags<<<1, 256, 0, stream>>>();               // stream-ordered before main

  cde_main<true ><<<256, 1024, 0, stream>>>(t, z0, X, b1, b2, b3, mb, sb, d_out);
  cde_main<false><<<256, 1024, 0, stream>>>(t, z0, X, b1, b2, b3, mb, sb, d_out);
  (void)in_sizes; (void)n_in; (void)out_size; (void)d_ws; (void)ws_size;
}

// Round 6
// 28904.657 us; speedup vs baseline: 3.5149x; 3.5149x over previous
//
#include <hip/hip_runtime.h>

// NeuralCDEDecoder: B=512, T=257, IN=32, H=128, BN=256, OUT=64, K_SUB=4.
// R11: exactly the R9 structure (4-way h-split, 256 blocks = 64 groups x 4
// h-quarters, 1 block/CU; flag-protocol exchange with [E]/[F] barriers)
// with ONE protocol change: the flag POST and the spin POLL are RELAXED
// agent-scope atomics (were RELEASE/ACQUIRE).
//   Why: on gfx950 the agent coherence point is past the per-XCD L2, so
//   ACQUIRE loads invalidate L2 on EVERY spin iteration and RELEASE stores
//   write L2 back -- an invalidation storm that evicted the streamed
//   W1/W2/W3 working set every stage (R6/R9 FETCH ~440KB/stage = full
//   per-XCD weight refetch; R10's 2-poll ring made it 2.6MB/stage).
//   Ordering without fences: barrier [E]'s vmcnt(0) drain completes the
//   sc1 atomic g_zx data stores at the coherence point before the flag
//   store issues; a reader observing the flag (also at the coherence
//   point) then finds the data there; barrier [F] orders its data loads.
// W3: 16/64 ntiles cached in LDS (128KB), 48 streamed from L2 (384KB/stage).
// fp32 state, hi/lo bf16 activations.

using short8   = __attribute__((ext_vector_type(8))) short;
using float4v  = __attribute__((ext_vector_type(4))) float;

__device__ unsigned short g_w1p[32768];
__device__ unsigned short g_w2p[65536];
__device__ unsigned short g_w3p[1048576];
__device__ unsigned short g_mwp[8192];
__device__ unsigned short g_swp[8192];

__device__ int   g_flag[256];                 // last stage posted per block
__device__ float g_zx[2 * 64 * 4 * 256];      // [parity][group][quarter][8rows*32dims]

__global__ void reset_flags(){
  if (threadIdx.x < 256) g_flag[threadIdx.x] = -1;
}

__device__ __forceinline__ unsigned short* pack_dst(int which){
  switch (which){
    case 0:  return g_w1p;
    case 1:  return g_w2p;
    case 2:  return g_w3p;
    case 3:  return g_mwp;
    default: return g_swp;
  }
}

__device__ __forceinline__ float bf2f(unsigned short h){
  union { unsigned int u; float f; } v; v.u = ((unsigned int)h) << 16; return v.f;
}
__device__ __forceinline__ unsigned short f2bf(float f){
  union { float f; unsigned int u; } v; v.f = f;
  unsigned int u = v.u;
  return (unsigned short)((u + 0x7FFFu + ((u >> 16) & 1u)) >> 16);  // RNE
}
template<bool BF16> __device__ __forceinline__ float loadf(const void* p, long i){
  if constexpr (BF16) return bf2f(((const unsigned short*)p)[i]);
  else                return ((const float*)p)[i];
}
// t[0]=0.0 always; bytes 2..3 are high half of f32 t[0] (=0) or bf16 t[1] (!=0).
__device__ __forceinline__ bool input_is_bf16(const void* t){
  return ((const unsigned short*)t)[1] != 0;
}
__device__ __forceinline__ float tanh_f(float x){
  float e = __builtin_amdgcn_exp2f(x * 2.88539008177793f);          // e^{2x}
  return 1.f - 2.f * __builtin_amdgcn_rcpf(e + 1.f);
}
__device__ __forceinline__ float softplus_f(float x){
  if (x > 20.f) return x;
  float e = __builtin_amdgcn_exp2f(x * 1.44269504088896f);
  return __builtin_amdgcn_logf(1.f + e) * 0.693147180559945f;       // log2->ln
}
// Sum across each 16-lane row; full sum lands in lane 15 of the row (VALU DPP).
__device__ __forceinline__ float row_sum16(float v){
  int x;
  x = __builtin_amdgcn_update_dpp(0, __float_as_int(v), 0x118, 0xF, 0xF, true); // row_shr:8
  v += __int_as_float(x);
  x = __builtin_amdgcn_update_dpp(0, __float_as_int(v), 0x114, 0xF, 0xF, true); // row_shr:4
  v += __int_as_float(x);
  x = __builtin_amdgcn_update_dpp(0, __float_as_int(v), 0x112, 0xF, 0xF, true); // row_shr:2
  v += __int_as_float(x);
  x = __builtin_amdgcn_update_dpp(0, __float_as_int(v), 0x111, 0xF, 0xF, true); // row_shr:1
  v += __int_as_float(x);
  return v;
}

// Pack row-major [K,N] weight into fragment order:
// tile (nt,kt) -> 512 bf16 at ((nt*KT+kt)<<9); elem (lane,j) = W[kt*32+(lane>>4)*8+j][nt*16+(lane&15)]
template<bool BF16>
__global__ __launch_bounds__(256)
void pack_weight(const void* __restrict__ src, int which,
                 int K, int N, const void* __restrict__ tchk){
  if (input_is_bf16(tchk) != BF16) return;
  unsigned short* dst = pack_dst(which);
  const int KT = K >> 5;
  const long total = (long)(N >> 4) * KT * 512;
  for (long e = (long)blockIdx.x * blockDim.x + threadIdx.x; e < total;
       e += (long)gridDim.x * blockDim.x){
    int  r    = (int)(e & 511);
    long tile = e >> 9;
    int  kt   = (int)(tile % KT);
    int  nt   = (int)(tile / KT);
    int  ln   = r >> 3, j = r & 7;
    int  k    = (kt << 5) + ((ln >> 4) << 3) + j;
    int  n    = (nt << 4) + (ln & 15);
    long si   = (long)k * N + n;
    dst[e] = BF16 ? ((const unsigned short*)src)[si] : f2bf(((const float*)src)[si]);
  }
}

#define STRZ 136   // z buffer row stride (bf16), 16 rows = hi/lo x 8 batch rows
#define STRH 264   // h buffer row stride (bf16), 16 rows = hi/lo x 8
#define STRV 36    // vf row stride (fp32), 8 rows x 32 own dims
#define STRD 33    // dxdt row stride (fp32), 8 rows
#define W3C_NT 16  // W3 ntiles cached in LDS (local ntiles 0..15 = waves 0..3)

template<bool BF16>
__global__ __launch_bounds__(1024, 4)
void cde_main(const void* __restrict__ tin,  const void* __restrict__ z0in,
              const void* __restrict__ Xin,
              const void* __restrict__ b1in, const void* __restrict__ b2in,
              const void* __restrict__ b3in, const void* __restrict__ mbin,
              const void* __restrict__ sbin,
              void* __restrict__ outv)
{
  if (input_is_bf16(tin) != BF16) return;

  const unsigned short* __restrict__ w1p = g_w1p;
  const unsigned short* __restrict__ w2p = g_w2p;
  const unsigned short* __restrict__ w3p = g_w3p;
  const unsigned short* __restrict__ mwp = g_mwp;
  const unsigned short* __restrict__ swp = g_swp;

  __shared__ __align__(16) unsigned short bufZ [16 * STRZ];
  __shared__ __align__(16) unsigned short bufH1[16 * STRH];
  __shared__ __align__(16) unsigned short bufH2[16 * STRH];
  __shared__ __align__(16) float          vfs  [ 8 * STRV];
  __shared__ __align__(16) float          dxs  [ 8 * STRD];
  __shared__ __align__(16) float          biasl[1664];              // b1|b2|b3q|mb|sb
  __shared__ __align__(16) unsigned short w3c  [W3C_NT * 8 * 512];  // 128KB

  const int tid  = threadIdx.x;
  const int lane = tid & 63;
  const int wv   = tid >> 6;          // wave 0..15
  const int c16  = lane & 15;         // MFMA A-row / B,D-col
  const int quad = lane >> 4;         // 0..3
  const int hq   = blockIdx.x & 3;    // h-quarter: h in [hq*32, hq*32+32)
  const int grp  = blockIdx.x >> 2;   // row group 0..63
  const int m0   = grp * 8;           // batch-row base (8 rows per group)

  // biases -> LDS (fp32); b3 only this block's quarter (1024 of 4096)
  for (int i = tid; i < 1664; i += 1024){
    float v;
    if      (i < 256)  v = loadf<BF16>(b1in, i);
    else if (i < 512)  v = loadf<BF16>(b2in, i - 256);
    else if (i < 1536) v = loadf<BF16>(b3in, hq * 1024 + (i - 512));
    else if (i < 1600) v = loadf<BF16>(mbin, i - 1536);
    else               v = loadf<BF16>(sbin, i - 1600);
    biasl[i] = v;
  }

  // W3 LDS cache: local ntiles [0,W3C_NT) = global ntiles hq*64 .. hq*64+15
  {
    const unsigned short* src = w3p + ((long)(hq * 512) << 9);
    for (int e = tid * 8; e < W3C_NT * 8 * 512; e += 1024 * 8)
      *(short8*)&w3c[e] = *(const short8*)&src[e];
  }

  // persistent W1/W2 fragments (wave wv owns ntile wv of each layer)
  short8 w1f[4], w2f[8];
  {
    const unsigned short* p1 = w1p + ((long)(wv * 4) << 9) + lane * 8;
    #pragma unroll
    for (int kt = 0; kt < 4; ++kt) w1f[kt] = *(const short8*)(p1 + (kt << 9));
    const unsigned short* p2 = w2p + ((long)(wv * 8) << 9) + lane * 8;
    #pragma unroll
    for (int kt = 0; kt < 8; ++kt) w2f[kt] = *(const short8*)(p2 + (kt << 9));
  }

  // per-thread z-state: thread owns dim zd of batch sub-row zm.
  // Threads whose zd falls in this block's h-quarter do the RK4 update and
  // publish; the other 768 threads receive the partners' slices.
  const int  zm   = tid >> 7;         // 0..7
  const int  zd   = tid & 127;        // 0..127
  const bool own  = (zd >> 5) == hq;
  const int  xidx = zm * 32 + (zd & 31);
  float z = loadf<BF16>(z0in, (long)(m0 + zm) * 128 + zd);
  float zacc = 0.f;
  {
    unsigned short h = f2bf(z);
    bufZ[(2 * zm    ) * STRZ + zd] = h;
    bufZ[(2 * zm + 1) * STRZ + zd] = f2bf(z - bf2f(h));
  }

  for (int ti = 0; ti < 256; ++ti){
    const float dt = loadf<BF16>(tin, ti + 1) - loadf<BF16>(tin, ti);
    const float hs = dt * 0.25f;                       // RK4 substep h
    if (tid < 256){
      const int m = tid >> 5, i = tid & 31;
      float xc = loadf<BF16>(Xin, ((long)(m0 + m) * 257 + ti    ) * 32 + i);
      float xn = loadf<BF16>(Xin, ((long)(m0 + m) * 257 + ti + 1) * 32 + i);
      dxs[m * STRD + i] = (xn - xc) / dt;
    }
    __syncthreads();                                   // dxs (and bufZ/bias/w3c) ready
    // dd[ih][s] = dxdt[m = quad*2+s][i = ih*16 + c16]
    float dd[2][2];
    #pragma unroll
    for (int ih = 0; ih < 2; ++ih)
      #pragma unroll
      for (int s = 0; s < 2; ++s)
        dd[ih][s] = dxs[(quad * 2 + s) * STRD + ih * 16 + c16];

    for (int sub = 0; sub < 4; ++sub){
      for (int st = 0; st < 4; ++st){
        const int stg = (ti << 4) + (sub << 2) + st;   // global stage 0..4095
        const int par = stg & 1;
        __syncthreads();                               // [A] stage input in bufZ

        // -------- layer 1: relu(z @ W1 + b1)  K=128 N=256 (1 ntile/wave, W1 in regs)
        {
          short8 a[4];
          #pragma unroll
          for (int kt = 0; kt < 4; ++kt)
            a[kt] = *(const short8*)&bufZ[c16 * STRZ + kt * 32 + quad * 8];
          float4v acc = { 0.f, 0.f, 0.f, 0.f };
          #pragma unroll
          for (int kt = 0; kt < 4; ++kt)
            acc = __builtin_amdgcn_mfma_f32_16x16x32_bf16(a[kt], w1f[kt], acc, 0, 0, 0);
          const float bv = biasl[wv * 16 + c16];
          #pragma unroll
          for (int s = 0; s < 2; ++s){
            float v = acc[2 * s] + acc[2 * s + 1] + bv;
            v = v > 0.f ? v : 0.f;
            unsigned short h = f2bf(v);
            const int row = quad * 4 + 2 * s;
            bufH1[ row      * STRH + wv * 16 + c16] = h;
            bufH1[(row + 1) * STRH + wv * 16 + c16] = f2bf(v - bf2f(h));
          }
        }
        __syncthreads();                               // [B]

        // -------- layer 2: relu(h1 @ W2 + b2)  K=256 N=256 (1 ntile/wave, W2 in regs)
        {
          short8 a[8];
          #pragma unroll
          for (int kt = 0; kt < 8; ++kt)
            a[kt] = *(const short8*)&bufH1[c16 * STRH + kt * 32 + quad * 8];
          float4v acc = { 0.f, 0.f, 0.f, 0.f };
          #pragma unroll
          for (int kt = 0; kt < 8; ++kt)
            acc = __builtin_amdgcn_mfma_f32_16x16x32_bf16(a[kt], w2f[kt], acc, 0, 0, 0);
          const float bv = biasl[256 + wv * 16 + c16];
          #pragma unroll
          for (int s = 0; s < 2; ++s){
            float v = acc[2 * s] + acc[2 * s + 1] + bv;
            v = v > 0.f ? v : 0.f;
            unsigned short h = f2bf(v);
            const int row = quad * 4 + 2 * s;
            bufH2[ row      * STRH + wv * 16 + c16] = h;
            bufH2[(row + 1) * STRH + wv * 16 + c16] = f2bf(v - bf2f(h));
          }
        }
        __syncthreads();                               // [C]

        // -------- layer 3 + contraction (own h-quarter only):
        // wave owns local ntiles wv*4 .. wv*4+3 (global hq*64 + that) -> 2 h/wave
        {
          short8 a[8];
          #pragma unroll
          for (int kt = 0; kt < 8; ++kt)
            a[kt] = *(const short8*)&bufH2[c16 * STRH + kt * 32 + quad * 8];

          const bool cached = (wv < 4);                // lnt < 16 -> in LDS
          #pragma unroll 1
          for (int j = 0; j < 4; j += 2){
            const int lnt = wv * 4 + j;
            float t0[2], t1[2];
            { // tile lnt: i in [0,16)
              float4v acc = { 0.f, 0.f, 0.f, 0.f };
              if (cached){
                const unsigned short* cp = &w3c[(lnt * 8) << 9] + lane * 8;
                #pragma unroll
                for (int kh = 0; kh < 2; ++kh){
                  short8 b[4];
                  #pragma unroll
                  for (int kt = 0; kt < 4; ++kt)
                    b[kt] = *(const short8*)(cp + ((kh * 4 + kt) << 9));
                  #pragma unroll
                  for (int kt = 0; kt < 4; ++kt)
                    acc = __builtin_amdgcn_mfma_f32_16x16x32_bf16(a[kh * 4 + kt], b[kt], acc, 0, 0, 0);
                }
              } else {
                const unsigned short* wp = w3p + (((long)(hq * 512 + lnt * 8)) << 9) + lane * 8;
                #pragma unroll
                for (int kh = 0; kh < 2; ++kh){
                  short8 b[4];
                  #pragma unroll
                  for (int kt = 0; kt < 4; ++kt)
                    b[kt] = *(const short8*)(wp + ((kh * 4 + kt) << 9));
                  #pragma unroll
                  for (int kt = 0; kt < 4; ++kt)
                    acc = __builtin_amdgcn_mfma_f32_16x16x32_bf16(a[kh * 4 + kt], b[kt], acc, 0, 0, 0);
                }
              }
              const float bv = biasl[512 + lnt * 16 + c16];
              #pragma unroll
              for (int s = 0; s < 2; ++s)
                t0[s] = tanh_f(acc[2 * s] + acc[2 * s + 1] + bv) * dd[0][s];
            }
            { // tile lnt+1: i in [16,32) + reduce + vf write
              const int nt = lnt + 1;
              float4v acc = { 0.f, 0.f, 0.f, 0.f };
              if (cached){
                const unsigned short* cp = &w3c[(nt * 8) << 9] + lane * 8;
                #pragma unroll
                for (int kh = 0; kh < 2; ++kh){
                  short8 b[4];
                  #pragma unroll
                  for (int kt = 0; kt < 4; ++kt)
                    b[kt] = *(const short8*)(cp + ((kh * 4 + kt) << 9));
                  #pragma unroll
                  for (int kt = 0; kt < 4; ++kt)
                    acc = __builtin_amdgcn_mfma_f32_16x16x32_bf16(a[kh * 4 + kt], b[kt], acc, 0, 0, 0);
                }
              } else {
                const unsigned short* wp = w3p + (((long)(hq * 512 + nt * 8)) << 9) + lane * 8;
                #pragma unroll
                for (int kh = 0; kh < 2; ++kh){
                  short8 b[4];
                  #pragma unroll
                  for (int kt = 0; kt < 4; ++kt)
                    b[kt] = *(const short8*)(wp + ((kh * 4 + kt) << 9));
                  #pragma unroll
                  for (int kt = 0; kt < 4; ++kt)
                    acc = __builtin_amdgcn_mfma_f32_16x16x32_bf16(a[kh * 4 + kt], b[kt], acc, 0, 0, 0);
                }
              }
              const float bv = biasl[512 + nt * 16 + c16];
              #pragma unroll
              for (int s = 0; s < 2; ++s)
                t1[s] = tanh_f(acc[2 * s] + acc[2 * s + 1] + bv) * dd[1][s];
              const int hl = lnt >> 1;                 // local h index 0..31
              #pragma unroll
              for (int s = 0; s < 2; ++s){
                float r = row_sum16(t0[s] + t1[s]);
                if (c16 == 15) vfs[(quad * 2 + s) * STRV + hl] = r;
              }
            }
          }
        }
        __syncthreads();                               // [D] own-quarter vfs ready

        // -------- RK4 combine (own quarter) + publish; receive partner quarters
        if (own){
          const float k = vfs[zm * STRV + (zd & 31)];
          float nin;
          if (st == 0){
            zacc = z + (hs * (1.f / 6.f)) * k;
            nin  = z + 0.5f * hs * k;
          } else if (st == 1){
            zacc += (hs * (1.f / 3.f)) * k;
            nin   = z + 0.5f * hs * k;
          } else if (st == 2){
            zacc += (hs * (1.f / 3.f)) * k;
            nin   = z + hs * k;
          } else {
            z    = zacc + (hs * (1.f / 6.f)) * k;
            nin  = z;
          }
          __hip_atomic_store((int*)&g_zx[((par * 64 + grp) * 4 + hq) * 256 + xidx],
                             __float_as_int(nin),
                             __ATOMIC_RELAXED, __HIP_MEMORY_SCOPE_AGENT);
          unsigned short h = f2bf(nin);
          bufZ[(2 * zm    ) * STRZ + zd] = h;
          bufZ[(2 * zm + 1) * STRZ + zd] = f2bf(nin - bf2f(h));
        }
        __syncthreads();                               // [E] vmcnt-drains publish stores
        // RELAXED post/poll: no L2 invalidate/writeback (agent atomics are
        // already coherent at the agent point; [E]/[F] provide ordering).
        if (tid == 0)
          __hip_atomic_store(&g_flag[blockIdx.x], stg,
                             __ATOMIC_RELAXED, __HIP_MEMORY_SCOPE_AGENT);
        if (tid < 3){
          const int p = (grp << 2) | ((hq + 1 + tid) & 3);
          while (__hip_atomic_load(&g_flag[p],
                                   __ATOMIC_RELAXED, __HIP_MEMORY_SCOPE_AGENT) < stg)
            __builtin_amdgcn_s_sleep(2);
        }
        __syncthreads();                               // [F] partner slices visible
        if (!own){
          const int q = zd >> 5;
          int u = __hip_atomic_load(
                    (const int*)&g_zx[((par * 64 + grp) * 4 + q) * 256 + xidx],
                    __ATOMIC_RELAXED, __HIP_MEMORY_SCOPE_AGENT);
          float v = __int_as_float(u);
          unsigned short h = f2bf(v);
          bufZ[(2 * zm    ) * STRZ + zd] = h;
          bufZ[(2 * zm + 1) * STRZ + zd] = f2bf(v - bf2f(h));
        }
      } // st
    } // sub

    __syncthreads();                                   // bufZ holds z(t[ti+1])
    // -------- decoder: hq==0 writes mean, hq==1 writes std (full z in bufZ)
    if (hq < 2 && wv < 4){
      short8 a[4];
      #pragma unroll
      for (int kt = 0; kt < 4; ++kt)
        a[kt] = *(const short8*)&bufZ[c16 * STRZ + kt * 32 + quad * 8];
      const int  nt    = wv;
      const bool isStd = (hq == 1);
      const unsigned short* wp = (isStd ? swp : mwp) + ((long)(nt * 4) << 9) + lane * 8;
      short8 b[4];
      #pragma unroll
      for (int kt = 0; kt < 4; ++kt) b[kt] = *(const short8*)(wp + (kt << 9));
      float4v acc = { 0.f, 0.f, 0.f, 0.f };
      #pragma unroll
      for (int kt = 0; kt < 4; ++kt)
        acc = __builtin_amdgcn_mfma_f32_16x16x32_bf16(a[kt], b[kt], acc, 0, 0, 0);
      const float bv    = biasl[(isStd ? 1600 : 1536) + nt * 16 + c16];
      const long  obase = isStd ? 8388608L : 0L;       // B*(T-1)*OUT
      #pragma unroll
      for (int s = 0; s < 2; ++s){
        float v = acc[2 * s] + acc[2 * s + 1] + bv;
        if (isStd) v = softplus_f(v);
        long oi = obase + ((long)(m0 + quad * 2 + s) * 256 + ti) * 64 + nt * 16 + c16;
        if constexpr (BF16) ((unsigned short*)outv)[oi] = f2bf(v);
        else                ((float*)outv)[oi] = v;
      }
    }
  } // ti
}

extern "C" void kernel_launch(void* const* d_in, const int* in_sizes, int n_in,
                              void* d_out, int out_size, void* d_ws, size_t ws_size,
                              hipStream_t stream)
{
  const void* t  = d_in[0];
  const void* z0 = d_in[1];
  const void* X  = d_in[2];
  const void* W1 = d_in[3];
  const void* b1 = d_in[4];
  const void* W2 = d_in[5];
  const void* b2 = d_in[6];
  const void* W3 = d_in[7];
  const void* b3 = d_in[8];
  const void* mW = d_in[9];
  const void* mb = d_in[10];
  const void* sW = d_in[11];
  const void* sb = d_in[12];

  // Both dtype variants launched; each checks input dtype and the
  // non-matching one returns immediately (t[0]==0.0 discriminator).
  pack_weight<true ><<<256, 256, 0, stream>>>(W1, 0, 128,  256, t);
  pack_weight<true ><<<256, 256, 0, stream>>>(W2, 1, 256,  256, t);
  pack_weight<true ><<<512, 256, 0, stream>>>(W3, 2, 256, 4096, t);
  pack_weight<true ><<< 64, 256, 0, stream>>>(mW, 3, 128,   64, t);
  pack_weight<true ><<< 64, 256, 0, stream>>>(sW, 4, 128,   64, t);
  pack_weight<false><<<256, 256, 0, stream>>>(W1, 0, 128,  256, t);
  pack_weight<false><<<256, 256, 0, stream>>>(W2, 1, 256,  256, t);
  pack_weight<false><<<512, 256, 0, stream>>>(W3, 2, 256, 4096, t);
  pack_weight<false><<< 64, 256, 0, stream>>>(mW, 3, 128,   64, t);
  pack_weight<false><<< 64, 256, 0, stream>>>(sW, 4, 128,   64, t);

  reset_flags<<<1, 256, 0, stream>>>();               // stream-ordered before main

  cde_main<true ><<<256, 1024, 0, stream>>>(t, z0, X, b1, b2, b3, mb, sb, d_out);
  cde_main<false><<<256, 1024, 0, stream>>>(t, z0, X, b1, b2, b3, mb, sb, d_out);
  (void)in_sizes; (void)n_in; (void)out_size; (void)d_ws; (void)ws_size;
}

// Round 7
// 28759.491 us; speedup vs baseline: 3.5326x; 1.0050x over previous
//
#include <hip/hip_runtime.h>

// NeuralCDEDecoder: B=512, T=257, IN=32, H=128, BN=256, OUT=64, K_SUB=4.
// R12: R11 (4-way h-split, 256 blocks, relaxed flag protocol -- 28.9ms)
// plus two numerics-identical changes:
//  1. W1/W2 fragments forced VGPR-resident via volatile asm "+v" defs
//     (R6/R9/R11 all showed VGPR_Count=64: the allocator rematerialized
//     the loads every stage = 192KB/stage/CU of redundant L2 traffic).
//  2. W3 LDS cache remapped: cache tiles lnt%4==0 (one per wave, slot=wv)
//     instead of tiles 0..15 (waves 0..3). Every wave now streams 3 of 4
//     tiles -> the [D]-barrier critical path (max over waves) shortens.
// W3: 16/64 ntiles cached in LDS (128KB), 48 streamed from L2.
// fp32 state, hi/lo bf16 activations.

using short8   = __attribute__((ext_vector_type(8))) short;
using float4v  = __attribute__((ext_vector_type(4))) float;

__device__ unsigned short g_w1p[32768];
__device__ unsigned short g_w2p[65536];
__device__ unsigned short g_w3p[1048576];
__device__ unsigned short g_mwp[8192];
__device__ unsigned short g_swp[8192];

__device__ int   g_flag[256];                 // last stage posted per block
__device__ float g_zx[2 * 64 * 4 * 256];      // [parity][group][quarter][8rows*32dims]

__global__ void reset_flags(){
  if (threadIdx.x < 256) g_flag[threadIdx.x] = -1;
}

__device__ __forceinline__ unsigned short* pack_dst(int which){
  switch (which){
    case 0:  return g_w1p;
    case 1:  return g_w2p;
    case 2:  return g_w3p;
    case 3:  return g_mwp;
    default: return g_swp;
  }
}

__device__ __forceinline__ float bf2f(unsigned short h){
  union { unsigned int u; float f; } v; v.u = ((unsigned int)h) << 16; return v.f;
}
__device__ __forceinline__ unsigned short f2bf(float f){
  union { float f; unsigned int u; } v; v.f = f;
  unsigned int u = v.u;
  return (unsigned short)((u + 0x7FFFu + ((u >> 16) & 1u)) >> 16);  // RNE
}
template<bool BF16> __device__ __forceinline__ float loadf(const void* p, long i){
  if constexpr (BF16) return bf2f(((const unsigned short*)p)[i]);
  else                return ((const float*)p)[i];
}
// t[0]=0.0 always; bytes 2..3 are high half of f32 t[0] (=0) or bf16 t[1] (!=0).
__device__ __forceinline__ bool input_is_bf16(const void* t){
  return ((const unsigned short*)t)[1] != 0;
}
__device__ __forceinline__ float tanh_f(float x){
  float e = __builtin_amdgcn_exp2f(x * 2.88539008177793f);          // e^{2x}
  return 1.f - 2.f * __builtin_amdgcn_rcpf(e + 1.f);
}
__device__ __forceinline__ float softplus_f(float x){
  if (x > 20.f) return x;
  float e = __builtin_amdgcn_exp2f(x * 1.44269504088896f);
  return __builtin_amdgcn_logf(1.f + e) * 0.693147180559945f;       // log2->ln
}
// Sum across each 16-lane row; full sum lands in lane 15 of the row (VALU DPP).
__device__ __forceinline__ float row_sum16(float v){
  int x;
  x = __builtin_amdgcn_update_dpp(0, __float_as_int(v), 0x118, 0xF, 0xF, true); // row_shr:8
  v += __int_as_float(x);
  x = __builtin_amdgcn_update_dpp(0, __float_as_int(v), 0x114, 0xF, 0xF, true); // row_shr:4
  v += __int_as_float(x);
  x = __builtin_amdgcn_update_dpp(0, __float_as_int(v), 0x112, 0xF, 0xF, true); // row_shr:2
  v += __int_as_float(x);
  x = __builtin_amdgcn_update_dpp(0, __float_as_int(v), 0x111, 0xF, 0xF, true); // row_shr:1
  v += __int_as_float(x);
  return v;
}

// Pack row-major [K,N] weight into fragment order:
// tile (nt,kt) -> 512 bf16 at ((nt*KT+kt)<<9); elem (lane,j) = W[kt*32+(lane>>4)*8+j][nt*16+(lane&15)]
template<bool BF16>
__global__ __launch_bounds__(256)
void pack_weight(const void* __restrict__ src, int which,
                 int K, int N, const void* __restrict__ tchk){
  if (input_is_bf16(tchk) != BF16) return;
  unsigned short* dst = pack_dst(which);
  const int KT = K >> 5;
  const long total = (long)(N >> 4) * KT * 512;
  for (long e = (long)blockIdx.x * blockDim.x + threadIdx.x; e < total;
       e += (long)gridDim.x * blockDim.x){
    int  r    = (int)(e & 511);
    long tile = e >> 9;
    int  kt   = (int)(tile % KT);
    int  nt   = (int)(tile / KT);
    int  ln   = r >> 3, j = r & 7;
    int  k    = (kt << 5) + ((ln >> 4) << 3) + j;
    int  n    = (nt << 4) + (ln & 15);
    long si   = (long)k * N + n;
    dst[e] = BF16 ? ((const unsigned short*)src)[si] : f2bf(((const float*)src)[si]);
  }
}

#define STRZ 136   // z buffer row stride (bf16), 16 rows = hi/lo x 8 batch rows
#define STRH 264   // h buffer row stride (bf16), 16 rows = hi/lo x 8
#define STRV 36    // vf row stride (fp32), 8 rows x 32 own dims
#define STRD 33    // dxdt row stride (fp32), 8 rows
#define W3C_NT 16  // W3 ntiles cached in LDS: global quarter-tiles {0,4,8,...,60}

template<bool BF16>
__global__ __launch_bounds__(1024, 4)
void cde_main(const void* __restrict__ tin,  const void* __restrict__ z0in,
              const void* __restrict__ Xin,
              const void* __restrict__ b1in, const void* __restrict__ b2in,
              const void* __restrict__ b3in, const void* __restrict__ mbin,
              const void* __restrict__ sbin,
              void* __restrict__ outv)
{
  if (input_is_bf16(tin) != BF16) return;

  const unsigned short* __restrict__ w1p = g_w1p;
  const unsigned short* __restrict__ w2p = g_w2p;
  const unsigned short* __restrict__ w3p = g_w3p;
  const unsigned short* __restrict__ mwp = g_mwp;
  const unsigned short* __restrict__ swp = g_swp;

  __shared__ __align__(16) unsigned short bufZ [16 * STRZ];
  __shared__ __align__(16) unsigned short bufH1[16 * STRH];
  __shared__ __align__(16) unsigned short bufH2[16 * STRH];
  __shared__ __align__(16) float          vfs  [ 8 * STRV];
  __shared__ __align__(16) float          dxs  [ 8 * STRD];
  __shared__ __align__(16) float          biasl[1664];              // b1|b2|b3q|mb|sb
  __shared__ __align__(16) unsigned short w3c  [W3C_NT * 4096];     // 128KB

  const int tid  = threadIdx.x;
  const int lane = tid & 63;
  const int wv   = tid >> 6;          // wave 0..15
  const int c16  = lane & 15;         // MFMA A-row / B,D-col
  const int quad = lane >> 4;         // 0..3
  const int hq   = blockIdx.x & 3;    // h-quarter: h in [hq*32, hq*32+32)
  const int grp  = blockIdx.x >> 2;   // row group 0..63
  const int m0   = grp * 8;           // batch-row base (8 rows per group)

  // biases -> LDS (fp32); b3 only this block's quarter (1024 of 4096)
  for (int i = tid; i < 1664; i += 1024){
    float v;
    if      (i < 256)  v = loadf<BF16>(b1in, i);
    else if (i < 512)  v = loadf<BF16>(b2in, i - 256);
    else if (i < 1536) v = loadf<BF16>(b3in, hq * 1024 + (i - 512));
    else if (i < 1600) v = loadf<BF16>(mbin, i - 1536);
    else               v = loadf<BF16>(sbin, i - 1600);
    biasl[i] = v;
  }

  // W3 LDS cache: slot s holds quarter-tile s*4 (one cached tile per wave).
  for (int e = tid * 8; e < W3C_NT * 4096; e += 1024 * 8){
    const int s = e >> 12;             // cached slot 0..15
    const int o = e & 4095;            // offset within tile (shorts)
    *(short8*)&w3c[e] =
      *(const short8*)&w3p[(((long)(hq * 512 + s * 32)) << 9) + o];
  }

  // persistent W1/W2 fragments (wave wv owns ntile wv of each layer).
  // Volatile asm "+v" defs: the values become asm results -> cannot be
  // rematerialized from the loads -> stay VGPR-resident across the loop.
  short8 w1f[4], w2f[8];
  {
    const unsigned short* p1 = w1p + ((long)(wv * 4) << 9) + lane * 8;
    #pragma unroll
    for (int kt = 0; kt < 4; ++kt) w1f[kt] = *(const short8*)(p1 + (kt << 9));
    const unsigned short* p2 = w2p + ((long)(wv * 8) << 9) + lane * 8;
    #pragma unroll
    for (int kt = 0; kt < 8; ++kt) w2f[kt] = *(const short8*)(p2 + (kt << 9));
    #pragma unroll
    for (int kt = 0; kt < 4; ++kt) asm volatile("" : "+v"(w1f[kt]));
    #pragma unroll
    for (int kt = 0; kt < 8; ++kt) asm volatile("" : "+v"(w2f[kt]));
  }

  // per-thread z-state: thread owns dim zd of batch sub-row zm.
  // Threads whose zd falls in this block's h-quarter do the RK4 update and
  // publish; the other 768 threads receive the partners' slices.
  const int  zm   = tid >> 7;         // 0..7
  const int  zd   = tid & 127;        // 0..127
  const bool own  = (zd >> 5) == hq;
  const int  xidx = zm * 32 + (zd & 31);
  float z = loadf<BF16>(z0in, (long)(m0 + zm) * 128 + zd);
  float zacc = 0.f;
  {
    unsigned short h = f2bf(z);
    bufZ[(2 * zm    ) * STRZ + zd] = h;
    bufZ[(2 * zm + 1) * STRZ + zd] = f2bf(z - bf2f(h));
  }

  for (int ti = 0; ti < 256; ++ti){
    const float dt = loadf<BF16>(tin, ti + 1) - loadf<BF16>(tin, ti);
    const float hs = dt * 0.25f;                       // RK4 substep h
    if (tid < 256){
      const int m = tid >> 5, i = tid & 31;
      float xc = loadf<BF16>(Xin, ((long)(m0 + m) * 257 + ti    ) * 32 + i);
      float xn = loadf<BF16>(Xin, ((long)(m0 + m) * 257 + ti + 1) * 32 + i);
      dxs[m * STRD + i] = (xn - xc) / dt;
    }
    __syncthreads();                                   // dxs (and bufZ/bias/w3c) ready
    // dd[ih][s] = dxdt[m = quad*2+s][i = ih*16 + c16]
    float dd[2][2];
    #pragma unroll
    for (int ih = 0; ih < 2; ++ih)
      #pragma unroll
      for (int s = 0; s < 2; ++s)
        dd[ih][s] = dxs[(quad * 2 + s) * STRD + ih * 16 + c16];

    for (int sub = 0; sub < 4; ++sub){
      for (int st = 0; st < 4; ++st){
        const int stg = (ti << 4) + (sub << 2) + st;   // global stage 0..4095
        const int par = stg & 1;
        __syncthreads();                               // [A] stage input in bufZ

        // -------- layer 1: relu(z @ W1 + b1)  K=128 N=256 (1 ntile/wave, W1 in regs)
        {
          short8 a[4];
          #pragma unroll
          for (int kt = 0; kt < 4; ++kt)
            a[kt] = *(const short8*)&bufZ[c16 * STRZ + kt * 32 + quad * 8];
          float4v acc = { 0.f, 0.f, 0.f, 0.f };
          #pragma unroll
          for (int kt = 0; kt < 4; ++kt)
            acc = __builtin_amdgcn_mfma_f32_16x16x32_bf16(a[kt], w1f[kt], acc, 0, 0, 0);
          const float bv = biasl[wv * 16 + c16];
          #pragma unroll
          for (int s = 0; s < 2; ++s){
            float v = acc[2 * s] + acc[2 * s + 1] + bv;
            v = v > 0.f ? v : 0.f;
            unsigned short h = f2bf(v);
            const int row = quad * 4 + 2 * s;
            bufH1[ row      * STRH + wv * 16 + c16] = h;
            bufH1[(row + 1) * STRH + wv * 16 + c16] = f2bf(v - bf2f(h));
          }
        }
        __syncthreads();                               // [B]

        // -------- layer 2: relu(h1 @ W2 + b2)  K=256 N=256 (1 ntile/wave, W2 in regs)
        {
          short8 a[8];
          #pragma unroll
          for (int kt = 0; kt < 8; ++kt)
            a[kt] = *(const short8*)&bufH1[c16 * STRH + kt * 32 + quad * 8];
          float4v acc = { 0.f, 0.f, 0.f, 0.f };
          #pragma unroll
          for (int kt = 0; kt < 8; ++kt)
            acc = __builtin_amdgcn_mfma_f32_16x16x32_bf16(a[kt], w2f[kt], acc, 0, 0, 0);
          const float bv = biasl[256 + wv * 16 + c16];
          #pragma unroll
          for (int s = 0; s < 2; ++s){
            float v = acc[2 * s] + acc[2 * s + 1] + bv;
            v = v > 0.f ? v : 0.f;
            unsigned short h = f2bf(v);
            const int row = quad * 4 + 2 * s;
            bufH2[ row      * STRH + wv * 16 + c16] = h;
            bufH2[(row + 1) * STRH + wv * 16 + c16] = f2bf(v - bf2f(h));
          }
        }
        __syncthreads();                               // [C]

        // -------- layer 3 + contraction (own h-quarter only):
        // wave owns local ntiles wv*4 .. wv*4+3; tile wv*4 is LDS-cached
        {
          short8 a[8];
          #pragma unroll
          for (int kt = 0; kt < 8; ++kt)
            a[kt] = *(const short8*)&bufH2[c16 * STRH + kt * 32 + quad * 8];

          #pragma unroll 1
          for (int j = 0; j < 4; j += 2){
            const int lnt = wv * 4 + j;
            float t0[2], t1[2];
            { // tile lnt: i in [0,16)  (j==0 -> cached in LDS slot wv)
              float4v acc = { 0.f, 0.f, 0.f, 0.f };
              if (j == 0){
                const unsigned short* cp = &w3c[wv * 4096] + lane * 8;
                #pragma unroll
                for (int kh = 0; kh < 2; ++kh){
                  short8 b[4];
                  #pragma unroll
                  for (int kt = 0; kt < 4; ++kt)
                    b[kt] = *(const short8*)(cp + ((kh * 4 + kt) << 9));
                  #pragma unroll
                  for (int kt = 0; kt < 4; ++kt)
                    acc = __builtin_amdgcn_mfma_f32_16x16x32_bf16(a[kh * 4 + kt], b[kt], acc, 0, 0, 0);
                }
              } else {
                const unsigned short* wp = w3p + (((long)(hq * 512 + lnt * 8)) << 9) + lane * 8;
                #pragma unroll
                for (int kh = 0; kh < 2; ++kh){
                  short8 b[4];
                  #pragma unroll
                  for (int kt = 0; kt < 4; ++kt)
                    b[kt] = *(const short8*)(wp + ((kh * 4 + kt) << 9));
                  #pragma unroll
                  for (int kt = 0; kt < 4; ++kt)
                    acc = __builtin_amdgcn_mfma_f32_16x16x32_bf16(a[kh * 4 + kt], b[kt], acc, 0, 0, 0);
                }
              }
              const float bv = biasl[512 + lnt * 16 + c16];
              #pragma unroll
              for (int s = 0; s < 2; ++s)
                t0[s] = tanh_f(acc[2 * s] + acc[2 * s + 1] + bv) * dd[0][s];
            }
            { // tile lnt+1: i in [16,32) + reduce + vf write (always streamed)
              const int nt = lnt + 1;
              float4v acc = { 0.f, 0.f, 0.f, 0.f };
              {
                const unsigned short* wp = w3p + (((long)(hq * 512 + nt * 8)) << 9) + lane * 8;
                #pragma unroll
                for (int kh = 0; kh < 2; ++kh){
                  short8 b[4];
                  #pragma unroll
                  for (int kt = 0; kt < 4; ++kt)
                    b[kt] = *(const short8*)(wp + ((kh * 4 + kt) << 9));
                  #pragma unroll
                  for (int kt = 0; kt < 4; ++kt)
                    acc = __builtin_amdgcn_mfma_f32_16x16x32_bf16(a[kh * 4 + kt], b[kt], acc, 0, 0, 0);
                }
              }
              const float bv = biasl[512 + nt * 16 + c16];
              #pragma unroll
              for (int s = 0; s < 2; ++s)
                t1[s] = tanh_f(acc[2 * s] + acc[2 * s + 1] + bv) * dd[1][s];
              const int hl = lnt >> 1;                 // local h index 0..31
              #pragma unroll
              for (int s = 0; s < 2; ++s){
                float r = row_sum16(t0[s] + t1[s]);
                if (c16 == 15) vfs[(quad * 2 + s) * STRV + hl] = r;
              }
            }
          }
        }
        __syncthreads();                               // [D] own-quarter vfs ready

        // -------- RK4 combine (own quarter) + publish; receive partner quarters
        if (own){
          const float k = vfs[zm * STRV + (zd & 31)];
          float nin;
          if (st == 0){
            zacc = z + (hs * (1.f / 6.f)) * k;
            nin  = z + 0.5f * hs * k;
          } else if (st == 1){
            zacc += (hs * (1.f / 3.f)) * k;
            nin   = z + 0.5f * hs * k;
          } else if (st == 2){
            zacc += (hs * (1.f / 3.f)) * k;
            nin   = z + hs * k;
          } else {
            z    = zacc + (hs * (1.f / 6.f)) * k;
            nin  = z;
          }
          __hip_atomic_store((int*)&g_zx[((par * 64 + grp) * 4 + hq) * 256 + xidx],
                             __float_as_int(nin),
                             __ATOMIC_RELAXED, __HIP_MEMORY_SCOPE_AGENT);
          unsigned short h = f2bf(nin);
          bufZ[(2 * zm    ) * STRZ + zd] = h;
          bufZ[(2 * zm + 1) * STRZ + zd] = f2bf(nin - bf2f(h));
        }
        __syncthreads();                               // [E] vmcnt-drains publish stores
        // RELAXED post/poll (R11): no L2 invalidate/writeback storms.
        if (tid == 0)
          __hip_atomic_store(&g_flag[blockIdx.x], stg,
                             __ATOMIC_RELAXED, __HIP_MEMORY_SCOPE_AGENT);
        if (tid < 3){
          const int p = (grp << 2) | ((hq + 1 + tid) & 3);
          while (__hip_atomic_load(&g_flag[p],
                                   __ATOMIC_RELAXED, __HIP_MEMORY_SCOPE_AGENT) < stg)
            __builtin_amdgcn_s_sleep(2);
        }
        __syncthreads();                               // [F] partner slices visible
        if (!own){
          const int q = zd >> 5;
          int u = __hip_atomic_load(
                    (const int*)&g_zx[((par * 64 + grp) * 4 + q) * 256 + xidx],
                    __ATOMIC_RELAXED, __HIP_MEMORY_SCOPE_AGENT);
          float v = __int_as_float(u);
          unsigned short h = f2bf(v);
          bufZ[(2 * zm    ) * STRZ + zd] = h;
          bufZ[(2 * zm + 1) * STRZ + zd] = f2bf(v - bf2f(h));
        }
      } // st
    } // sub

    __syncthreads();                                   // bufZ holds z(t[ti+1])
    // -------- decoder: hq==0 writes mean, hq==1 writes std (full z in bufZ)
    if (hq < 2 && wv < 4){
      short8 a[4];
      #pragma unroll
      for (int kt = 0; kt < 4; ++kt)
        a[kt] = *(const short8*)&bufZ[c16 * STRZ + kt * 32 + quad * 8];
      const int  nt    = wv;
      const bool isStd = (hq == 1);
      const unsigned short* wp = (isStd ? swp : mwp) + ((long)(nt * 4) << 9) + lane * 8;
      short8 b[4];
      #pragma unroll
      for (int kt = 0; kt < 4; ++kt) b[kt] = *(const short8*)(wp + (kt << 9));
      float4v acc = { 0.f, 0.f, 0.f, 0.f };
      #pragma unroll
      for (int kt = 0; kt < 4; ++kt)
        acc = __builtin_amdgcn_mfma_f32_16x16x32_bf16(a[kt], b[kt], acc, 0, 0, 0);
      const float bv    = biasl[(isStd ? 1600 : 1536) + nt * 16 + c16];
      const long  obase = isStd ? 8388608L : 0L;       // B*(T-1)*OUT
      #pragma unroll
      for (int s = 0; s < 2; ++s){
        float v = acc[2 * s] + acc[2 * s + 1] + bv;
        if (isStd) v = softplus_f(v);
        long oi = obase + ((long)(m0 + quad * 2 + s) * 256 + ti) * 64 + nt * 16 + c16;
        if constexpr (BF16) ((unsigned short*)outv)[oi] = f2bf(v);
        else                ((float*)outv)[oi] = v;
      }
    }
  } // ti
}

extern "C" void kernel_launch(void* const* d_in, const int* in_sizes, int n_in,
                              void* d_out, int out_size, void* d_ws, size_t ws_size,
                              hipStream_t stream)
{
  const void* t  = d_in[0];
  const void* z0 = d_in[1];
  const void* X  = d_in[2];
  const void* W1 = d_in[3];
  const void* b1 = d_in[4];
  const void* W2 = d_in[5];
  const void* b2 = d_in[6];
  const void* W3 = d_in[7];
  const void* b3 = d_in[8];
  const void* mW = d_in[9];
  const void* mb = d_in[10];
  const void* sW = d_in[11];
  const void* sb = d_in[12];

  // Both dtype variants launched; each checks input dtype and the
  // non-matching one returns immediately (t[0]==0.0 discriminator).
  pack_weight<true ><<<256, 256, 0, stream>>>(W1, 0, 128,  256, t);
  pack_weight<true ><<<256, 256, 0, stream>>>(W2, 1, 256,  256, t);
  pack_weight<true ><<<512, 256, 0, stream>>>(W3, 2, 256, 4096, t);
  pack_weight<true ><<< 64, 256, 0, stream>>>(mW, 3, 128,   64, t);
  pack_weight<true ><<< 64, 256, 0, stream>>>(sW, 4, 128,   64, t);
  pack_weight<false><<<256, 256, 0, stream>>>(W1, 0, 128,  256, t);
  pack_weight<false><<<256, 256, 0, stream>>>(W2, 1, 256,  256, t);
  pack_weight<false><<<512, 256, 0, stream>>>(W3, 2, 256, 4096, t);
  pack_weight<false><<< 64, 256, 0, stream>>>(mW, 3, 128,   64, t);
  pack_weight<false><<< 64, 256, 0, stream>>>(sW, 4, 128,   64, t);

  reset_flags<<<1, 256, 0, stream>>>();               // stream-ordered before main

  cde_main<true ><<<256, 1024, 0, stream>>>(t, z0, X, b1, b2, b3, mb, sb, d_out);
  cde_main<false><<<256, 1024, 0, stream>>>(t, z0, X, b1, b2, b3, mb, sb, d_out);
  (void)in_sizes; (void)n_in; (void)out_size; (void)d_ws; (void)ws_size;
}